// Round 1
// baseline (1456.648 us; speedup 1.0000x reference)
//
#include <hip/hip_runtime.h>
#include <hip/hip_fp16.h>

#define TPB 256

__device__ __forceinline__ float silu_f(float v) {
    return v * (1.0f / (1.0f + __expf(-v)));
}

__global__ __launch_bounds__(TPB, 2)
void fused_net(const float* __restrict__ x,
               const float* __restrict__ w1,  const float* __restrict__ b1,
               const float* __restrict__ lng, const float* __restrict__ lnb,
               const float* __restrict__ w2,  const float* __restrict__ b2,
               const float* __restrict__ ew1, const float* __restrict__ eb1,
               const float* __restrict__ ew2, const float* __restrict__ eb2,
               const float* __restrict__ gw1, const float* __restrict__ gb1,
               const float* __restrict__ gw2, const float* __restrict__ gb2,
               const float* __restrict__ sw,  const float* __restrict__ sb,
               const float* __restrict__ hw1, const float* __restrict__ hb1,
               const float* __restrict__ hw2, const float* __restrict__ hb2,
               float* __restrict__ out, int B)
{
    // Single time-shared LDS activation buffer, thread-private column t.
    // Layout [row][thread]: lanes access consecutive 2B at fixed row ->
    // 2 lanes/bank = conflict-free. 128*256*2 = 65536 B exactly.
    __shared__ __half act[128][TPB];

    const int t = threadIdx.x;
    const long r = (long)blockIdx.x * TPB + t;
    if (r >= B) return;

    // ---------------- stem1: h[128] = x[r,:] @ w1 + b1 ----------------
    float h[128];
    #pragma unroll
    for (int j = 0; j < 128; ++j) h[j] = b1[j];

    const float4* __restrict__ xr = reinterpret_cast<const float4*>(x + r * 256);
    #pragma unroll 2
    for (int k4 = 0; k4 < 64; ++k4) {
        const float4 xv = xr[k4];
        const float* wr0 = w1 + (k4 * 4) * 128;
        #pragma unroll
        for (int j = 0; j < 128; ++j) h[j] = fmaf(xv.x, wr0[j],       h[j]);
        #pragma unroll
        for (int j = 0; j < 128; ++j) h[j] = fmaf(xv.y, wr0[128 + j], h[j]);
        #pragma unroll
        for (int j = 0; j < 128; ++j) h[j] = fmaf(xv.z, wr0[256 + j], h[j]);
        #pragma unroll
        for (int j = 0; j < 128; ++j) h[j] = fmaf(xv.w, wr0[384 + j], h[j]);
    }

    // ---------------- LayerNorm(128) + SiLU, stage to LDS ----------------
    float mu = 0.f;
    #pragma unroll
    for (int j = 0; j < 128; ++j) mu += h[j];
    mu *= (1.0f / 128.0f);
    float var = 0.f;
    #pragma unroll
    for (int j = 0; j < 128; ++j) { float d = h[j] - mu; var = fmaf(d, d, var); }
    const float rs = rsqrtf(var * (1.0f / 128.0f) + 1e-5f);
    #pragma unroll
    for (int j = 0; j < 128; ++j) {
        float v = (h[j] - mu) * rs * lng[j] + lnb[j];
        act[j][t] = __float2half(silu_f(v));
    }

    // ---------------- stem2: hb[64] = silu(h @ w2 + b2) ----------------
    float hb[64];
    #pragma unroll
    for (int m = 0; m < 64; ++m) hb[m] = b2[m];
    #pragma unroll 2
    for (int j = 0; j < 128; ++j) {
        const float a = __half2float(act[j][t]);
        const float* wr = w2 + j * 64;
        #pragma unroll
        for (int m = 0; m < 64; ++m) hb[m] = fmaf(a, wr[m], hb[m]);
    }
    #pragma unroll
    for (int m = 0; m < 64; ++m) hb[m] = silu_f(hb[m]);

    // stage hb to LDS rows 0..63 (consumed with runtime j by gate/experts)
    #pragma unroll
    for (int m = 0; m < 64; ++m) act[m][t] = __float2half(hb[m]);

    // ---------------- gate: softmax(silu(hb@gw1+gb1)@gw2+gb2) ----------------
    float g[32];
    #pragma unroll
    for (int m = 0; m < 32; ++m) g[m] = gb1[m];
    #pragma unroll 2
    for (int j = 0; j < 64; ++j) {
        const float a = __half2float(act[j][t]);
        const float* wr = gw1 + j * 32;
        #pragma unroll
        for (int m = 0; m < 32; ++m) g[m] = fmaf(a, wr[m], g[m]);
    }
    float lg[4];
    #pragma unroll
    for (int o = 0; o < 4; ++o) lg[o] = gb2[o];
    #pragma unroll
    for (int j = 0; j < 32; ++j) {
        const float a = silu_f(g[j]);
        #pragma unroll
        for (int o = 0; o < 4; ++o) lg[o] = fmaf(a, gw2[j * 4 + o], lg[o]);
    }
    const float mx = fmaxf(fmaxf(lg[0], lg[1]), fmaxf(lg[2], lg[3]));
    float gwt[4]; float gs = 0.f;
    #pragma unroll
    for (int o = 0; o < 4; ++o) { gwt[o] = __expf(lg[o] - mx); gs += gwt[o]; }
    const float gsi = 1.0f / gs;
    #pragma unroll
    for (int o = 0; o < 4; ++o) gwt[o] *= gsi;

    // ---------------- 4 experts, gated accumulate into moe[64] ----------------
    float moe[64];
    #pragma unroll
    for (int m = 0; m < 64; ++m) moe[m] = 0.f;

    #pragma unroll 1
    for (int e = 0; e < 4; ++e) {
        const float* we1 = ew1 + e * (64 * 128);
        const float* we2 = ew2 + e * (128 * 64);
        const float* be1 = eb1 + e * 128;
        float e2[64];
        #pragma unroll
        for (int m = 0; m < 64; ++m) e2[m] = eb2[e * 64 + m];

        // process e1 in two halves of 64 to cap live registers at ~215
        #pragma unroll 1
        for (int mh = 0; mh < 2; ++mh) {
            float e1[64];
            #pragma unroll
            for (int m = 0; m < 64; ++m) e1[m] = be1[mh * 64 + m];
            #pragma unroll 2
            for (int j = 0; j < 64; ++j) {
                const float a = __half2float(act[j][t]);     // hb
                const float* wr = we1 + j * 128 + mh * 64;
                #pragma unroll
                for (int m = 0; m < 64; ++m) e1[m] = fmaf(a, wr[m], e1[m]);
            }
            // silu -> LDS rows 64..127 (so e2 can consume with runtime j)
            #pragma unroll
            for (int m = 0; m < 64; ++m) act[64 + m][t] = __float2half(silu_f(e1[m]));
            #pragma unroll 2
            for (int j = 0; j < 64; ++j) {
                const float a = __half2float(act[64 + j][t]);
                const float* wr = we2 + (mh * 64 + j) * 64;
                #pragma unroll
                for (int m = 0; m < 64; ++m) e2[m] = fmaf(a, wr[m], e2[m]);
            }
        }
        #pragma unroll
        for (int m = 0; m < 64; ++m) moe[m] = fmaf(gwt[e], silu_f(e2[m]), moe[m]);
    }

    // ---------------- shared trunk: feat = silu(moe @ sw + sb) ----------------
    #pragma unroll
    for (int m = 0; m < 64; ++m) act[m][t] = __float2half(moe[m]);
    float feat[64];
    #pragma unroll
    for (int m = 0; m < 64; ++m) feat[m] = sb[m];
    #pragma unroll 2
    for (int j = 0; j < 64; ++j) {
        const float a = __half2float(act[j][t]);
        const float* wr = sw + j * 64;
        #pragma unroll
        for (int m = 0; m < 64; ++m) feat[m] = fmaf(a, wr[m], feat[m]);
    }
    #pragma unroll
    for (int m = 0; m < 64; ++m) act[64 + m][t] = __float2half(silu_f(feat[m]));

    // ---------------- 3 heads ----------------
    #pragma unroll 1
    for (int k = 0; k < 3; ++k) {
        float hh[32];
        #pragma unroll
        for (int m = 0; m < 32; ++m) hh[m] = hb1[k * 32 + m];
        #pragma unroll 2
        for (int j = 0; j < 64; ++j) {
            const float a = __half2float(act[64 + j][t]);
            const float* wr = hw1 + k * (64 * 32) + j * 32;
            #pragma unroll
            for (int m = 0; m < 32; ++m) hh[m] = fmaf(a, wr[m], hh[m]);
        }
        float acc = hb2[k];
        #pragma unroll
        for (int m = 0; m < 32; ++m) acc = fmaf(silu_f(hh[m]), hw2[k * 32 + m], acc);
        out[r * 3 + k] = acc;
    }
}

extern "C" void kernel_launch(void* const* d_in, const int* in_sizes, int n_in,
                              void* d_out, int out_size, void* d_ws, size_t ws_size,
                              hipStream_t stream) {
    const float* x    = (const float*)d_in[0];
    const float* w1   = (const float*)d_in[1];
    const float* b1   = (const float*)d_in[2];
    const float* lng  = (const float*)d_in[3];
    const float* lnb  = (const float*)d_in[4];
    const float* w2   = (const float*)d_in[5];
    const float* b2   = (const float*)d_in[6];
    const float* ew1  = (const float*)d_in[7];
    const float* eb1  = (const float*)d_in[8];
    const float* ew2  = (const float*)d_in[9];
    const float* eb2  = (const float*)d_in[10];
    const float* gw1  = (const float*)d_in[11];
    const float* gb1  = (const float*)d_in[12];
    const float* gw2  = (const float*)d_in[13];
    const float* gb2  = (const float*)d_in[14];
    const float* sw   = (const float*)d_in[15];
    const float* sb   = (const float*)d_in[16];
    const float* hw1  = (const float*)d_in[17];
    const float* hb1  = (const float*)d_in[18];
    const float* hw2  = (const float*)d_in[19];
    const float* hb2  = (const float*)d_in[20];
    float* out = (float*)d_out;

    const int B = in_sizes[0] / 256;
    const int grid = (B + TPB - 1) / TPB;
    hipLaunchKernelGGL(fused_net, dim3(grid), dim3(TPB), 0, stream,
                       x, w1, b1, lng, lnb, w2, b2, ew1, eb1, ew2, eb2,
                       gw1, gb1, gw2, gb2, sw, sb, hw1, hb1, hw2, hb2, out, B);
}

// Round 2
// 256.231 us; speedup vs baseline: 5.6849x; 5.6849x over previous
//
#include <hip/hip_runtime.h>

typedef _Float16 f16;
typedef f16   f16x8 __attribute__((ext_vector_type(8)));
typedef float f32x4 __attribute__((ext_vector_type(4)));

#define MFMA16(a, b, c) __builtin_amdgcn_mfma_f32_16x16x32_f16((a), (b), (c), 0, 0, 0)

// LDS layout in f16 units (80 KB total -> 2 blocks/CU)
#define ACT1_OFF 0       // [128][128] stride 128 (also E1; FEAT reuses with stride 64)
#define ACT2_OFF 16384   // [128][64]  stride 64
#define W_OFF    24576   // 16384 f16 = 32 KB weight staging region
#define LDS_F16  40960

__device__ __forceinline__ float silu_f(float v) {
    return v / (1.0f + __expf(-v));
}

// Read an 8-f16 fragment (A or B^T) from swizzled LDS.
// row = row_base + (lane&15); k = k0 + 8*(lane>>4) + i  (i = 0..7 contiguous)
__device__ __forceinline__ f16x8 ld_frag(const f16* base, int stride16, int row_base, int k0) {
    const int lane = threadIdx.x & 63;
    const int r = row_base + (lane & 15);
    const int c = k0 + ((lane >> 4) << 3);
    const int off = r * stride16 + (c ^ ((r & 7) << 3));
    return *(const f16x8*)(base + off);
}

// Store a C fragment (16x16, f32x4) to swizzled LDS as f16.
// C layout (verified): col = lane&15, row = 4*(lane>>4) + g
__device__ __forceinline__ void st_frag(f16* base, int stride16, int row_base, int col_base, f32x4 v) {
    const int lane = threadIdx.x & 63;
    const int c = col_base + (lane & 15);
    #pragma unroll
    for (int g = 0; g < 4; ++g) {
        const int r = row_base + ((lane >> 4) << 2) + g;
        base[r * stride16 + (c ^ ((r & 7) << 3))] = (f16)v[g];
    }
}

// Load an A fragment of x straight from global (fp32 -> f16).
__device__ __forceinline__ f16x8 ld_x(const float* xrow_base, int ks) {
    const int lane = threadIdx.x & 63;
    const float* p = xrow_base + (long)(lane & 15) * 256 + ks * 32 + ((lane >> 4) << 3);
    const float4 u = *(const float4*)p;
    const float4 w = *(const float4*)(p + 4);
    f16x8 a;
    a[0] = (f16)u.x; a[1] = (f16)u.y; a[2] = (f16)u.z; a[3] = (f16)u.w;
    a[4] = (f16)w.x; a[5] = (f16)w.y; a[6] = (f16)w.z; a[7] = (f16)w.w;
    return a;
}

// Cooperative stage: global W[K][N] fp32 -> LDS Wt[n][k] f16, swizzled. N power of 2.
__device__ __forceinline__ void stage_wt(f16* dst, const float* g, int K, int N) {
    for (int idx = threadIdx.x; idx < K * N; idx += 256) {
        const int k = idx / N;
        const int n = idx - k * N;
        dst[n * K + (k ^ ((n & 7) << 3))] = (f16)g[idx];
    }
}

// Butterfly sum over the 16-lane column group (masks 1,2,4,8), element-wise on f32x4.
__device__ __forceinline__ f32x4 reduce16(f32x4 v) {
    #pragma unroll
    for (int m = 1; m <= 8; m <<= 1) {
        f32x4 o;
        #pragma unroll
        for (int i = 0; i < 4; ++i) o[i] = __shfl_xor(v[i], m, 64);
        v += o;
    }
    return v;
}

__global__ __launch_bounds__(256, 2)
void fused_net_mfma(const float* __restrict__ x,
                    const float* __restrict__ w1,  const float* __restrict__ b1,
                    const float* __restrict__ lng, const float* __restrict__ lnb,
                    const float* __restrict__ w2,  const float* __restrict__ b2,
                    const float* __restrict__ ew1, const float* __restrict__ eb1,
                    const float* __restrict__ ew2, const float* __restrict__ eb2,
                    const float* __restrict__ gw1, const float* __restrict__ gb1,
                    const float* __restrict__ gw2, const float* __restrict__ gb2,
                    const float* __restrict__ sw,  const float* __restrict__ sb,
                    const float* __restrict__ hw1, const float* __restrict__ hb1,
                    const float* __restrict__ hw2, const float* __restrict__ hb2,
                    float* __restrict__ out)
{
    __shared__ __align__(16) f16 lds[LDS_F16];
    f16* ACT1 = lds + ACT1_OFF;
    f16* ACT2 = lds + ACT2_OFF;
    f16* W    = lds + W_OFF;

    const int lane = threadIdx.x & 63;
    const int wv   = threadIdx.x >> 6;
    const int c    = lane & 15;
    const long blockRow = (long)blockIdx.x * 128;
    const int waveRow = wv * 32;

    // ================= stem1: h = x @ w1 + b1  (K=256, N=128) =================
    f32x4 acc[2][8];
    #pragma unroll
    for (int n = 0; n < 8; ++n) {
        const float bv = b1[n * 16 + c];
        f32x4 t = {bv, bv, bv, bv};
        acc[0][n] = t; acc[1][n] = t;
    }
    const float* xw = x + (blockRow + waveRow) * 256;

    #pragma unroll 1
    for (int half = 0; half < 2; ++half) {
        stage_wt(W, w1 + half * 128 * 128, 128, 128);
        __syncthreads();
        #pragma unroll
        for (int ks = 0; ks < 4; ++ks) {
            const f16x8 a0 = ld_x(xw,            half * 4 + ks);
            const f16x8 a1 = ld_x(xw + 16 * 256, half * 4 + ks);
            #pragma unroll
            for (int n = 0; n < 8; ++n) {
                const f16x8 b = ld_frag(W, 128, n * 16, ks * 32);
                acc[0][n] = MFMA16(a0, b, acc[0][n]);
                acc[1][n] = MFMA16(a1, b, acc[1][n]);
            }
        }
        __syncthreads();   // W reads complete before restage
    }

    // ================= LayerNorm(128) + SiLU -> ACT1 =================
    #pragma unroll
    for (int m = 0; m < 2; ++m) {
        f32x4 s = {0, 0, 0, 0}, q = {0, 0, 0, 0};
        #pragma unroll
        for (int n = 0; n < 8; ++n) { s += acc[m][n]; q += acc[m][n] * acc[m][n]; }
        s = reduce16(s); q = reduce16(q);
        const f32x4 mu = s * 0.0078125f;
        f32x4 rs;
        #pragma unroll
        for (int g = 0; g < 4; ++g) {
            const float var = q[g] * 0.0078125f - mu[g] * mu[g];
            rs[g] = rsqrtf(var + 1e-5f);
        }
        #pragma unroll
        for (int n = 0; n < 8; ++n) {
            const float gg = lng[n * 16 + c], bb = lnb[n * 16 + c];
            f32x4 v;
            #pragma unroll
            for (int g = 0; g < 4; ++g)
                v[g] = silu_f((acc[m][n][g] - mu[g]) * rs[g] * gg + bb);
            st_frag(ACT1, 128, waveRow + m * 16, n * 16, v);
        }
    }
    stage_wt(W, w2, 128, 64);            // w2t [64][128]
    stage_wt(W + 8192, gw1, 64, 32);     // gw1t [32][64]
    __syncthreads();                     // ACT1 + W staging visible

    // ================= stem2: hb = silu(act1 @ w2 + b2)  (K=128, N=64) =================
    {
        f32x4 a2[2][4];
        #pragma unroll
        for (int n = 0; n < 4; ++n) {
            const float bv = b2[n * 16 + c];
            f32x4 t = {bv, bv, bv, bv};
            a2[0][n] = t; a2[1][n] = t;
        }
        #pragma unroll
        for (int ks = 0; ks < 4; ++ks) {
            const f16x8 a0 = ld_frag(ACT1, 128, waveRow,      ks * 32);
            const f16x8 a1 = ld_frag(ACT1, 128, waveRow + 16, ks * 32);
            #pragma unroll
            for (int n = 0; n < 4; ++n) {
                const f16x8 b = ld_frag(W, 128, n * 16, ks * 32);
                a2[0][n] = MFMA16(a0, b, a2[0][n]);
                a2[1][n] = MFMA16(a1, b, a2[1][n]);
            }
        }
        #pragma unroll
        for (int m = 0; m < 2; ++m)
            #pragma unroll
            for (int n = 0; n < 4; ++n) {
                f32x4 v;
                #pragma unroll
                for (int g = 0; g < 4; ++g) v[g] = silu_f(a2[m][n][g]);
                st_frag(ACT2, 64, waveRow + m * 16, n * 16, v);
            }
    }
    __syncthreads();   // ACT2 ready; gw1t untouched

    // ================= gate: softmax(silu(hb@gw1+gb1)@gw2+gb2) =================
    f32x4 gwt[2][4];   // [m][reg] -> 4 gate weights (e in vector lanes)
    {
        f32x4 ag[2][2];
        #pragma unroll
        for (int n = 0; n < 2; ++n) {
            const float bv = gb1[n * 16 + c];
            f32x4 t = {bv, bv, bv, bv};
            ag[0][n] = t; ag[1][n] = t;
        }
        #pragma unroll
        for (int ks = 0; ks < 2; ++ks) {
            const f16x8 a0 = ld_frag(ACT2, 64, waveRow,      ks * 32);
            const f16x8 a1 = ld_frag(ACT2, 64, waveRow + 16, ks * 32);
            #pragma unroll
            for (int n = 0; n < 2; ++n) {
                const f16x8 b = ld_frag(W + 8192, 64, n * 16, ks * 32);
                ag[0][n] = MFMA16(a0, b, ag[0][n]);
                ag[1][n] = MFMA16(a1, b, ag[1][n]);
            }
        }
        const f32x4 gb2v = *(const f32x4*)gb2;
        #pragma unroll
        for (int m = 0; m < 2; ++m) {
            f32x4 pg[4] = {{0,0,0,0},{0,0,0,0},{0,0,0,0},{0,0,0,0}};
            #pragma unroll
            for (int n = 0; n < 2; ++n) {
                const int j = n * 16 + c;
                const f32x4 w4 = *(const f32x4*)(gw2 + j * 4);
                #pragma unroll
                for (int g = 0; g < 4; ++g)
                    pg[g] += silu_f(ag[m][n][g]) * w4;
            }
            #pragma unroll
            for (int g = 0; g < 4; ++g) {
                f32x4 l = reduce16(pg[g]) + gb2v;
                const float mx = fmaxf(fmaxf(l[0], l[1]), fmaxf(l[2], l[3]));
                f32x4 e;
                #pragma unroll
                for (int o = 0; o < 4; ++o) e[o] = __expf(l[o] - mx);
                const float inv = 1.0f / (e[0] + e[1] + e[2] + e[3]);
                gwt[m][g] = e * inv;
            }
        }
    }
    __syncthreads();   // gw1t reads complete before expert staging

    // ================= 4 experts (K=64 -> N=128 -> K=128 -> N=64), gated =================
    f32x4 moe[2][4] = {{{0,0,0,0},{0,0,0,0},{0,0,0,0},{0,0,0,0}},
                       {{0,0,0,0},{0,0,0,0},{0,0,0,0},{0,0,0,0}}};
    #pragma unroll
    for (int e = 0; e < 4; ++e) {
        stage_wt(W,        ew1 + e * 64 * 128, 64, 128);   // ew1t [128][64]
        stage_wt(W + 8192, ew2 + e * 128 * 64, 128, 64);   // ew2t [64][128]
        __syncthreads();
        // e1
        f32x4 a1acc[2][8];
        #pragma unroll
        for (int n = 0; n < 8; ++n) {
            const float bv = eb1[e * 128 + n * 16 + c];
            f32x4 t = {bv, bv, bv, bv};
            a1acc[0][n] = t; a1acc[1][n] = t;
        }
        #pragma unroll
        for (int ks = 0; ks < 2; ++ks) {
            const f16x8 a0 = ld_frag(ACT2, 64, waveRow,      ks * 32);
            const f16x8 a1 = ld_frag(ACT2, 64, waveRow + 16, ks * 32);
            #pragma unroll
            for (int n = 0; n < 8; ++n) {
                const f16x8 b = ld_frag(W, 64, n * 16, ks * 32);
                a1acc[0][n] = MFMA16(a0, b, a1acc[0][n]);
                a1acc[1][n] = MFMA16(a1, b, a1acc[1][n]);
            }
        }
        #pragma unroll
        for (int m = 0; m < 2; ++m)
            #pragma unroll
            for (int n = 0; n < 8; ++n) {
                f32x4 v;
                #pragma unroll
                for (int g = 0; g < 4; ++g) v[g] = silu_f(a1acc[m][n][g]);
                st_frag(ACT1, 128, waveRow + m * 16, n * 16, v);   // E1
            }
        __syncthreads();
        // e2
        f32x4 a2acc[2][4];
        #pragma unroll
        for (int n = 0; n < 4; ++n) {
            const float bv = eb2[e * 64 + n * 16 + c];
            f32x4 t = {bv, bv, bv, bv};
            a2acc[0][n] = t; a2acc[1][n] = t;
        }
        #pragma unroll
        for (int ks = 0; ks < 4; ++ks) {
            const f16x8 a0 = ld_frag(ACT1, 128, waveRow,      ks * 32);
            const f16x8 a1 = ld_frag(ACT1, 128, waveRow + 16, ks * 32);
            #pragma unroll
            for (int n = 0; n < 4; ++n) {
                const f16x8 b = ld_frag(W + 8192, 128, n * 16, ks * 32);
                a2acc[0][n] = MFMA16(a0, b, a2acc[0][n]);
                a2acc[1][n] = MFMA16(a1, b, a2acc[1][n]);
            }
        }
        #pragma unroll
        for (int m = 0; m < 2; ++m)
            #pragma unroll
            for (int n = 0; n < 4; ++n)
                #pragma unroll
                for (int g = 0; g < 4; ++g)
                    moe[m][n][g] += silu_f(a2acc[m][n][g]) * gwt[m][g][e];
        __syncthreads();   // W + E1 reads done before next iteration's staging
    }

    // write moe -> ACT2 (hb is dead)
    #pragma unroll
    for (int m = 0; m < 2; ++m)
        #pragma unroll
        for (int n = 0; n < 4; ++n)
            st_frag(ACT2, 64, waveRow + m * 16, n * 16, moe[m][n]);
    stage_wt(W, sw, 64, 64);                                   // swt [64][64]
    #pragma unroll
    for (int h = 0; h < 3; ++h)
        stage_wt(W + 4096 + h * 32 * 64, hw1 + h * 64 * 32, 64, 32);  // hw1t [96][64]
    __syncthreads();

    // ================= shared: feat = silu(moe @ sw + sb)  (K=64, N=64) =================
    {
        f32x4 as[2][4];
        #pragma unroll
        for (int n = 0; n < 4; ++n) {
            const float bv = sb[n * 16 + c];
            f32x4 t = {bv, bv, bv, bv};
            as[0][n] = t; as[1][n] = t;
        }
        #pragma unroll
        for (int ks = 0; ks < 2; ++ks) {
            const f16x8 a0 = ld_frag(ACT2, 64, waveRow,      ks * 32);
            const f16x8 a1 = ld_frag(ACT2, 64, waveRow + 16, ks * 32);
            #pragma unroll
            for (int n = 0; n < 4; ++n) {
                const f16x8 b = ld_frag(W, 64, n * 16, ks * 32);
                as[0][n] = MFMA16(a0, b, as[0][n]);
                as[1][n] = MFMA16(a1, b, as[1][n]);
            }
        }
        #pragma unroll
        for (int m = 0; m < 2; ++m)
            #pragma unroll
            for (int n = 0; n < 4; ++n) {
                f32x4 v;
                #pragma unroll
                for (int g = 0; g < 4; ++g) v[g] = silu_f(as[m][n][g]);
                st_frag(ACT1, 64, waveRow + m * 16, n * 16, v);   // FEAT, stride 64
            }
    }
    __syncthreads();

    // ================= heads: hh = silu(feat @ hw1 + hb1); out = hh @ hw2 + hb2 =================
    {
        f32x4 ah[2][6];
        #pragma unroll
        for (int n = 0; n < 6; ++n) {
            const float bv = hb1[(n >> 1) * 32 + (n & 1) * 16 + c];
            f32x4 t = {bv, bv, bv, bv};
            ah[0][n] = t; ah[1][n] = t;
        }
        #pragma unroll
        for (int ks = 0; ks < 2; ++ks) {
            const f16x8 a0 = ld_frag(ACT1, 64, waveRow,      ks * 32);
            const f16x8 a1 = ld_frag(ACT1, 64, waveRow + 16, ks * 32);
            #pragma unroll
            for (int n = 0; n < 6; ++n) {
                const f16x8 b = ld_frag(W + 4096, 64, n * 16, ks * 32);
                ah[0][n] = MFMA16(a0, b, ah[0][n]);
                ah[1][n] = MFMA16(a1, b, ah[1][n]);
            }
        }
        const float hb2_0 = hb2[0], hb2_1 = hb2[1], hb2_2 = hb2[2];
        #pragma unroll
        for (int m = 0; m < 2; ++m) {
            f32x4 ph[3] = {{0,0,0,0},{0,0,0,0},{0,0,0,0}};  // [head][reg]
            #pragma unroll
            for (int n = 0; n < 6; ++n) {
                const int head = n >> 1;
                const int j = (n & 1) * 16 + c;
                const float w2v = hw2[head * 32 + j];
                #pragma unroll
                for (int g = 0; g < 4; ++g)
                    ph[head][g] += silu_f(ah[m][n][g]) * w2v;
            }
            #pragma unroll
            for (int h = 0; h < 3; ++h) ph[h] = reduce16(ph[h]);
            #pragma unroll
            for (int g = 0; g < 4; ++g) {
                const long row = blockRow + waveRow + m * 16 + ((lane >> 4) << 2) + g;
                if (c < 3) {
                    const float r0 = ph[0][g] + hb2_0;
                    const float r1 = ph[1][g] + hb2_1;
                    const float r2 = ph[2][g] + hb2_2;
                    const float v = (c == 0) ? r0 : ((c == 1) ? r1 : r2);
                    out[row * 3 + c] = v;
                }
            }
        }
    }
}

extern "C" void kernel_launch(void* const* d_in, const int* in_sizes, int n_in,
                              void* d_out, int out_size, void* d_ws, size_t ws_size,
                              hipStream_t stream) {
    const float* x    = (const float*)d_in[0];
    const float* w1   = (const float*)d_in[1];
    const float* b1   = (const float*)d_in[2];
    const float* lng  = (const float*)d_in[3];
    const float* lnb  = (const float*)d_in[4];
    const float* w2   = (const float*)d_in[5];
    const float* b2   = (const float*)d_in[6];
    const float* ew1  = (const float*)d_in[7];
    const float* eb1  = (const float*)d_in[8];
    const float* ew2  = (const float*)d_in[9];
    const float* eb2  = (const float*)d_in[10];
    const float* gw1  = (const float*)d_in[11];
    const float* gb1  = (const float*)d_in[12];
    const float* gw2  = (const float*)d_in[13];
    const float* gb2  = (const float*)d_in[14];
    const float* sw   = (const float*)d_in[15];
    const float* sb   = (const float*)d_in[16];
    const float* hw1  = (const float*)d_in[17];
    const float* hb1  = (const float*)d_in[18];
    const float* hw2  = (const float*)d_in[19];
    const float* hb2  = (const float*)d_in[20];
    float* out = (float*)d_out;

    const int B = in_sizes[0] / 256;
    const int grid = B / 128;
    hipLaunchKernelGGL(fused_net_mfma, dim3(grid), dim3(256), 0, stream,
                       x, w1, b1, lng, lnb, w2, b2, ew1, eb1, ew2, eb2,
                       gw1, gb1, gw2, gb2, sw, sb, hw1, hb1, hw2, hb2, out);
}

// Round 3
// 135.444 us; speedup vs baseline: 10.7547x; 1.8918x over previous
//
#include <hip/hip_runtime.h>

typedef _Float16 f16;
typedef f16   f16x4 __attribute__((ext_vector_type(4)));
typedef f16   f16x8 __attribute__((ext_vector_type(8)));
typedef float f32x4 __attribute__((ext_vector_type(4)));

#define MFMA16(a, b, c) __builtin_amdgcn_mfma_f32_16x16x32_f16((a), (b), (c), 0, 0, 0)

// ---- weight image offsets in d_ws (f16 units) ----
#define IMG_W1   0        // 32768: two halves of [128n][128k]
#define IMG_W2   32768    // 8192:  [64n][128k]
#define IMG_GW1  40960    // 2048:  [32n][64k]
#define IMG_EW1  43008    // 4*8192: [128n][64k]
#define IMG_EW2  75776    // 4*8192: [64n][128k]
#define IMG_SW   108544   // 4096:  [64n][64k]
#define IMG_HW1  112640   // 3*2048: [32n][64k]
#define IMG_TOT  118784   // 232 KB

__device__ __forceinline__ float silu_f(float v) {
    return v / (1.0f + __expf(-v));
}

// ============ prep kernel: fp32 W[K][N] -> f16 img[n][k ^ ((n&7)<<3)] ============
__device__ void conv_seg(const float* __restrict__ src, f16* __restrict__ dst,
                         int K, int N, int tid, int nth) {
    for (int i = tid; i < K * N; i += nth) {
        const int k = i / N, n = i - k * N;
        dst[n * K + (k ^ ((n & 7) << 3))] = (f16)src[i];
    }
}

__global__ void prep_weights(const float* __restrict__ w1, const float* __restrict__ w2,
                             const float* __restrict__ gw1, const float* __restrict__ ew1,
                             const float* __restrict__ ew2, const float* __restrict__ sw,
                             const float* __restrict__ hw1, f16* __restrict__ ws) {
    const int tid = blockIdx.x * 256 + threadIdx.x;
    const int nth = gridDim.x * 256;
    conv_seg(w1,         ws + IMG_W1,         128, 128, tid, nth);
    conv_seg(w1 + 16384, ws + IMG_W1 + 16384, 128, 128, tid, nth);
    conv_seg(w2,         ws + IMG_W2,         128,  64, tid, nth);
    conv_seg(gw1,        ws + IMG_GW1,         64,  32, tid, nth);
    for (int e = 0; e < 4; ++e) {
        conv_seg(ew1 + e * 8192, ws + IMG_EW1 + e * 8192,  64, 128, tid, nth);
        conv_seg(ew2 + e * 8192, ws + IMG_EW2 + e * 8192, 128,  64, tid, nth);
    }
    conv_seg(sw, ws + IMG_SW, 64, 64, tid, nth);
    for (int h = 0; h < 3; ++h)
        conv_seg(hw1 + h * 2048, ws + IMG_HW1 + h * 2048, 64, 32, tid, nth);
}

// ============ async global->LDS staging (16B/lane, pre-swizzled source) ============
#define GLL16(g, l) __builtin_amdgcn_global_load_lds(                        \
    (const __attribute__((address_space(1))) void*)(g),                     \
    (__attribute__((address_space(3))) void*)(l), 16, 0, 0)

template<int S_F16>
__device__ __forceinline__ void stage_img(const f16* __restrict__ g, f16* l,
                                          int wv, int lane) {
    constexpr int QB = (S_F16 * 2) / 4;   // bytes per wave quarter
    constexpr int CALLS = QB / 1024;      // 64 lanes * 16B per call
    const char* gs = (const char*)g + wv * QB + lane * 16;
    char* ls = (char*)l + wv * QB;        // wave-uniform base; HW adds lane*16
    #pragma unroll
    for (int i = 0; i < CALLS; ++i)
        GLL16(gs + i * 1024, ls + i * 1024);
}

// ============ swizzle keys ============
// MODE 0: weight tiles (read-only)        key = (n&7)<<3
// MODE 1: ACT tiles, K=128 (read+write)   key = (r&15)<<3
// MODE 2: ACT tiles, K=64  (read+write)   key = (((r>>2)&3)<<1 | (r&1))<<3
__device__ __forceinline__ int swz_key(int mode, int r) {
    if (mode == 0) return (r & 7) << 3;
    if (mode == 1) return (r & 15) << 3;
    return ((((r >> 2) & 3) << 1) | (r & 1)) << 3;
}

template<int MODE>
__device__ __forceinline__ f16x8 ld_frag(const f16* base, int stride, int row_base, int k0) {
    const int lane = threadIdx.x & 63;
    const int r = row_base + (lane & 15);
    const int k = k0 + ((lane >> 4) << 3);
    return *(const f16x8*)(base + r * stride + (k ^ swz_key(MODE, r)));
}

template<int MODE>
__device__ __forceinline__ void st_frag(f16* base, int stride, int row_base, int col_base, f32x4 v) {
    const int lane = threadIdx.x & 63;
    const int c = col_base + (lane & 15);
    #pragma unroll
    for (int g = 0; g < 4; ++g) {
        const int r = row_base + ((lane >> 4) << 2) + g;
        base[r * stride + (c ^ swz_key(MODE, r))] = (f16)v[g];
    }
}

// coalesced x[128 rows][128 k-half] fp32 -> ACT1 f16, MODE-1 swizzled
__device__ __forceinline__ void stage_x(const float* __restrict__ xsrc, f16* ACT1, int half) {
    const int t = threadIdx.x;
    #pragma unroll 8
    for (int i = 0; i < 16; ++i) {
        const int idx4 = t + i * 256;
        const int r  = idx4 >> 5;
        const int kc = (idx4 & 31) << 2;
        const float4 v = *(const float4*)(xsrc + (long)r * 256 + half * 128 + kc);
        f16x4 o; o[0] = (f16)v.x; o[1] = (f16)v.y; o[2] = (f16)v.z; o[3] = (f16)v.w;
        *(f16x4*)(ACT1 + r * 128 + (kc ^ ((r & 15) << 3))) = o;
    }
}

__device__ __forceinline__ f32x4 reduce16(f32x4 v) {
    #pragma unroll
    for (int m = 1; m <= 8; m <<= 1) {
        f32x4 o;
        #pragma unroll
        for (int i = 0; i < 4; ++i) o[i] = __shfl_xor(v[i], m, 64);
        v += o;
    }
    return v;
}

__global__ __launch_bounds__(256, 2)
void fused_net_mfma(const float* __restrict__ x,   const f16* __restrict__ wsp,
                    const float* __restrict__ b1,  const float* __restrict__ lng,
                    const float* __restrict__ lnb, const float* __restrict__ b2,
                    const float* __restrict__ eb1, const float* __restrict__ eb2,
                    const float* __restrict__ gb1, const float* __restrict__ gw2,
                    const float* __restrict__ gb2, const float* __restrict__ sb,
                    const float* __restrict__ hb1, const float* __restrict__ hw2,
                    const float* __restrict__ hb2, float* __restrict__ out)
{
    __shared__ __align__(16) f16 lds[40960];   // 80 KB -> 2 blocks/CU
    f16* ACT1 = lds;            // 16384 f16: [128][128] MODE1 (x, LN, E1; feat as [128][64] MODE2)
    f16* ACT2 = lds + 16384;    //  8192 f16: [128][64]  MODE2 (hb, moe)
    f16* WA   = lds + 24576;    //  8192 f16 weight slot A
    f16* WB   = lds + 32768;    //  8192 f16 weight slot B (stem1 uses WA..WB as one 32KB tile)

    const int lane = threadIdx.x & 63;
    const int wv   = threadIdx.x >> 6;
    const int c    = lane & 15;
    const long blockRow = (long)blockIdx.x * 128;
    const int waveRow = wv * 32;
    const float* xblk = x + blockRow * 256;

    // ---- P0: stage w1 half0 (32KB across WA+WB) + x half0 ----
    stage_img<16384>(wsp + IMG_W1, WA, wv, lane);
    stage_x(xblk, ACT1, 0);
    __syncthreads();

    // ---- stem1: h = x @ w1 + b1 (K=256 in halves, N=128) ----
    f32x4 acc[2][8];
    #pragma unroll
    for (int n = 0; n < 8; ++n) {
        const float bv = b1[n * 16 + c];
        f32x4 t = {bv, bv, bv, bv};
        acc[0][n] = t; acc[1][n] = t;
    }
    #pragma unroll
    for (int ks = 0; ks < 4; ++ks) {
        const f16x8 a0 = ld_frag<1>(ACT1, 128, waveRow,      ks * 32);
        const f16x8 a1 = ld_frag<1>(ACT1, 128, waveRow + 16, ks * 32);
        #pragma unroll
        for (int n = 0; n < 8; ++n) {
            const f16x8 b = ld_frag<0>(WA, 128, n * 16, ks * 32);
            acc[0][n] = MFMA16(a0, b, acc[0][n]);
            acc[1][n] = MFMA16(a1, b, acc[1][n]);
        }
    }
    __syncthreads();   // W + ACT1 free

    // ---- P2: stage w1 half1 + x half1 ----
    stage_img<16384>(wsp + IMG_W1 + 16384, WA, wv, lane);
    stage_x(xblk, ACT1, 1);
    __syncthreads();

    #pragma unroll
    for (int ks = 0; ks < 4; ++ks) {
        const f16x8 a0 = ld_frag<1>(ACT1, 128, waveRow,      ks * 32);
        const f16x8 a1 = ld_frag<1>(ACT1, 128, waveRow + 16, ks * 32);
        #pragma unroll
        for (int n = 0; n < 8; ++n) {
            const f16x8 b = ld_frag<0>(WA, 128, n * 16, ks * 32);
            acc[0][n] = MFMA16(a0, b, acc[0][n]);
            acc[1][n] = MFMA16(a1, b, acc[1][n]);
        }
    }

    // ---- LayerNorm(128) + SiLU -> ACT1 (own rows; no barrier needed) ----
    #pragma unroll
    for (int m = 0; m < 2; ++m) {
        f32x4 s = {0, 0, 0, 0}, q = {0, 0, 0, 0};
        #pragma unroll
        for (int n = 0; n < 8; ++n) { s += acc[m][n]; q += acc[m][n] * acc[m][n]; }
        s = reduce16(s); q = reduce16(q);
        const f32x4 mu = s * 0.0078125f;
        f32x4 rs;
        #pragma unroll
        for (int g = 0; g < 4; ++g) {
            const float var = q[g] * 0.0078125f - mu[g] * mu[g];
            rs[g] = rsqrtf(var + 1e-5f);
        }
        #pragma unroll
        for (int n = 0; n < 8; ++n) {
            const float gg = lng[n * 16 + c], bb = lnb[n * 16 + c];
            f32x4 v;
            #pragma unroll
            for (int g = 0; g < 4; ++g)
                v[g] = silu_f((acc[m][n][g] - mu[g]) * rs[g] * gg + bb);
            st_frag<1>(ACT1, 128, waveRow + m * 16, n * 16, v);
        }
    }
    __syncthreads();   // W free

    // ---- P4: stage w2 -> WA, gw1 -> WB ----
    stage_img<8192>(wsp + IMG_W2,  WA, wv, lane);
    stage_img<2048>(wsp + IMG_GW1, WB, wv, lane);
    __syncthreads();

    // ---- stem2: hb = silu(LN @ w2 + b2) (K=128, N=64) -> ACT2 ----
    {
        f32x4 a2[2][4];
        #pragma unroll
        for (int n = 0; n < 4; ++n) {
            const float bv = b2[n * 16 + c];
            f32x4 t = {bv, bv, bv, bv};
            a2[0][n] = t; a2[1][n] = t;
        }
        #pragma unroll
        for (int ks = 0; ks < 4; ++ks) {
            const f16x8 a0 = ld_frag<1>(ACT1, 128, waveRow,      ks * 32);
            const f16x8 a1 = ld_frag<1>(ACT1, 128, waveRow + 16, ks * 32);
            #pragma unroll
            for (int n = 0; n < 4; ++n) {
                const f16x8 b = ld_frag<0>(WA, 128, n * 16, ks * 32);
                a2[0][n] = MFMA16(a0, b, a2[0][n]);
                a2[1][n] = MFMA16(a1, b, a2[1][n]);
            }
        }
        #pragma unroll
        for (int m = 0; m < 2; ++m)
            #pragma unroll
            for (int n = 0; n < 4; ++n) {
                f32x4 v;
                #pragma unroll
                for (int g = 0; g < 4; ++g) v[g] = silu_f(a2[m][n][g]);
                st_frag<2>(ACT2, 64, waveRow + m * 16, n * 16, v);
            }
    }

    // ---- gate: softmax(silu(hb@gw1+gb1)@gw2+gb2) (same wave's ACT2 rows) ----
    f32x4 gwt[2][4];
    {
        f32x4 ag[2][2];
        #pragma unroll
        for (int n = 0; n < 2; ++n) {
            const float bv = gb1[n * 16 + c];
            f32x4 t = {bv, bv, bv, bv};
            ag[0][n] = t; ag[1][n] = t;
        }
        #pragma unroll
        for (int ks = 0; ks < 2; ++ks) {
            const f16x8 a0 = ld_frag<2>(ACT2, 64, waveRow,      ks * 32);
            const f16x8 a1 = ld_frag<2>(ACT2, 64, waveRow + 16, ks * 32);
            #pragma unroll
            for (int n = 0; n < 2; ++n) {
                const f16x8 b = ld_frag<0>(WB, 64, n * 16, ks * 32);
                ag[0][n] = MFMA16(a0, b, ag[0][n]);
                ag[1][n] = MFMA16(a1, b, ag[1][n]);
            }
        }
        const f32x4 gb2v = *(const f32x4*)gb2;
        #pragma unroll
        for (int m = 0; m < 2; ++m) {
            f32x4 pg[4] = {{0,0,0,0},{0,0,0,0},{0,0,0,0},{0,0,0,0}};
            #pragma unroll
            for (int n = 0; n < 2; ++n) {
                const int j = n * 16 + c;
                const f32x4 w4 = *(const f32x4*)(gw2 + j * 4);
                #pragma unroll
                for (int g = 0; g < 4; ++g)
                    pg[g] += silu_f(ag[m][n][g]) * w4;
            }
            #pragma unroll
            for (int g = 0; g < 4; ++g) {
                f32x4 l = reduce16(pg[g]) + gb2v;
                const float mx = fmaxf(fmaxf(l[0], l[1]), fmaxf(l[2], l[3]));
                f32x4 ee;
                #pragma unroll
                for (int o = 0; o < 4; ++o) ee[o] = __expf(l[o] - mx);
                const float inv = 1.0f / (ee[0] + ee[1] + ee[2] + ee[3]);
                gwt[m][g] = ee * inv;
            }
        }
    }
    __syncthreads();   // WA, WB free

    // ---- P6: stage ew1[0] -> WA ----
    stage_img<8192>(wsp + IMG_EW1, WA, wv, lane);
    __syncthreads();

    // ---- 4 experts, fully unrolled (gwt[..][e] must be a static index) ----
    f32x4 moe[2][4] = {{{0,0,0,0},{0,0,0,0},{0,0,0,0},{0,0,0,0}},
                       {{0,0,0,0},{0,0,0,0},{0,0,0,0},{0,0,0,0}}};
    #pragma unroll
    for (int e = 0; e < 4; ++e) {
        stage_img<8192>(wsp + IMG_EW2 + e * 8192, WB, wv, lane);   // hides under e1
        // e1: E1 = silu(hb @ ew1 + eb1) (K=64, N=128) in two N-halves
        #pragma unroll
        for (int mh = 0; mh < 2; ++mh) {
            f32x4 a1acc[2][4];
            #pragma unroll
            for (int n = 0; n < 4; ++n) {
                const float bv = eb1[e * 128 + mh * 64 + n * 16 + c];
                f32x4 t = {bv, bv, bv, bv};
                a1acc[0][n] = t; a1acc[1][n] = t;
            }
            #pragma unroll
            for (int ks = 0; ks < 2; ++ks) {
                const f16x8 a0 = ld_frag<2>(ACT2, 64, waveRow,      ks * 32);
                const f16x8 a1 = ld_frag<2>(ACT2, 64, waveRow + 16, ks * 32);
                #pragma unroll
                for (int n = 0; n < 4; ++n) {
                    const f16x8 b = ld_frag<0>(WA, 64, mh * 64 + n * 16, ks * 32);
                    a1acc[0][n] = MFMA16(a0, b, a1acc[0][n]);
                    a1acc[1][n] = MFMA16(a1, b, a1acc[1][n]);
                }
            }
            #pragma unroll
            for (int m = 0; m < 2; ++m)
                #pragma unroll
                for (int n = 0; n < 4; ++n) {
                    f32x4 v;
                    #pragma unroll
                    for (int g = 0; g < 4; ++g) v[g] = silu_f(a1acc[m][n][g]);
                    st_frag<1>(ACT1, 128, waveRow + m * 16, mh * 64 + n * 16, v);
                }
        }
        __syncthreads();   // WA free; WB (ew2) drained
        if (e < 3) stage_img<8192>(wsp + IMG_EW1 + (e + 1) * 8192, WA, wv, lane); // hides under e2
        // e2: moe += gate[e] * silu(E1 @ ew2 + eb2) (K=128, N=64)
        f32x4 a2acc[2][4];
        #pragma unroll
        for (int n = 0; n < 4; ++n) {
            const float bv = eb2[e * 64 + n * 16 + c];
            f32x4 t = {bv, bv, bv, bv};
            a2acc[0][n] = t; a2acc[1][n] = t;
        }
        #pragma unroll
        for (int ks = 0; ks < 4; ++ks) {
            const f16x8 a0 = ld_frag<1>(ACT1, 128, waveRow,      ks * 32);
            const f16x8 a1 = ld_frag<1>(ACT1, 128, waveRow + 16, ks * 32);
            #pragma unroll
            for (int n = 0; n < 4; ++n) {
                const f16x8 b = ld_frag<0>(WB, 128, n * 16, ks * 32);
                a2acc[0][n] = MFMA16(a0, b, a2acc[0][n]);
                a2acc[1][n] = MFMA16(a1, b, a2acc[1][n]);
            }
        }
        #pragma unroll
        for (int m = 0; m < 2; ++m)
            #pragma unroll
            for (int n = 0; n < 4; ++n)
                #pragma unroll
                for (int g = 0; g < 4; ++g)
                    moe[m][n][g] += silu_f(a2acc[m][n][g]) * gwt[m][g][e];
        __syncthreads();   // WB free; WA (next ew1) drained
    }

    // ---- moe -> ACT2 (hb dead); stage sw -> WA, hw1 -> WB ----
    #pragma unroll
    for (int m = 0; m < 2; ++m)
        #pragma unroll
        for (int n = 0; n < 4; ++n)
            st_frag<2>(ACT2, 64, waveRow + m * 16, n * 16, moe[m][n]);
    stage_img<4096>(wsp + IMG_SW,  WA, wv, lane);
    stage_img<6144>(wsp + IMG_HW1, WB, wv, lane);
    __syncthreads();

    // ---- shared: feat = silu(moe @ sw + sb) (K=64, N=64) -> ACT1 [128][64] ----
    {
        f32x4 as[2][4];
        #pragma unroll
        for (int n = 0; n < 4; ++n) {
            const float bv = sb[n * 16 + c];
            f32x4 t = {bv, bv, bv, bv};
            as[0][n] = t; as[1][n] = t;
        }
        #pragma unroll
        for (int ks = 0; ks < 2; ++ks) {
            const f16x8 a0 = ld_frag<2>(ACT2, 64, waveRow,      ks * 32);
            const f16x8 a1 = ld_frag<2>(ACT2, 64, waveRow + 16, ks * 32);
            #pragma unroll
            for (int n = 0; n < 4; ++n) {
                const f16x8 b = ld_frag<0>(WA, 64, n * 16, ks * 32);
                as[0][n] = MFMA16(a0, b, as[0][n]);
                as[1][n] = MFMA16(a1, b, as[1][n]);
            }
        }
        #pragma unroll
        for (int m = 0; m < 2; ++m)
            #pragma unroll
            for (int n = 0; n < 4; ++n) {
                f32x4 v;
                #pragma unroll
                for (int g = 0; g < 4; ++g) v[g] = silu_f(as[m][n][g]);
                st_frag<2>(ACT1, 64, waveRow + m * 16, n * 16, v);
            }
    }

    // ---- heads (own-wave ACT1 rows; no barrier needed) ----
    {
        f32x4 ah[2][6];
        #pragma unroll
        for (int n = 0; n < 6; ++n) {
            const float bv = hb1[(n >> 1) * 32 + (n & 1) * 16 + c];
            f32x4 t = {bv, bv, bv, bv};
            ah[0][n] = t; ah[1][n] = t;
        }
        #pragma unroll
        for (int ks = 0; ks < 2; ++ks) {
            const f16x8 a0 = ld_frag<2>(ACT1, 64, waveRow,      ks * 32);
            const f16x8 a1 = ld_frag<2>(ACT1, 64, waveRow + 16, ks * 32);
            #pragma unroll
            for (int n = 0; n < 6; ++n) {
                const f16x8 b = ld_frag<0>(WB + (n >> 1) * 2048, 64, (n & 1) * 16, ks * 32);
                ah[0][n] = MFMA16(a0, b, ah[0][n]);
                ah[1][n] = MFMA16(a1, b, ah[1][n]);
            }
        }
        const float hb2_0 = hb2[0], hb2_1 = hb2[1], hb2_2 = hb2[2];
        #pragma unroll
        for (int m = 0; m < 2; ++m) {
            f32x4 ph[3] = {{0,0,0,0},{0,0,0,0},{0,0,0,0}};
            #pragma unroll
            for (int n = 0; n < 6; ++n) {
                const int head = n >> 1;
                const int j = (n & 1) * 16 + c;
                const float w2v = hw2[head * 32 + j];
                #pragma unroll
                for (int g = 0; g < 4; ++g)
                    ph[head][g] += silu_f(ah[m][n][g]) * w2v;
            }
            #pragma unroll
            for (int h = 0; h < 3; ++h) ph[h] = reduce16(ph[h]);
            #pragma unroll
            for (int g = 0; g < 4; ++g) {
                const long row = blockRow + waveRow + m * 16 + ((lane >> 4) << 2) + g;
                if (c < 3) {
                    const float r0 = ph[0][g] + hb2_0;
                    const float r1 = ph[1][g] + hb2_1;
                    const float r2 = ph[2][g] + hb2_2;
                    out[row * 3 + c] = (c == 0) ? r0 : ((c == 1) ? r1 : r2);
                }
            }
        }
    }
}

extern "C" void kernel_launch(void* const* d_in, const int* in_sizes, int n_in,
                              void* d_out, int out_size, void* d_ws, size_t ws_size,
                              hipStream_t stream) {
    const float* x    = (const float*)d_in[0];
    const float* w1   = (const float*)d_in[1];
    const float* b1   = (const float*)d_in[2];
    const float* lng  = (const float*)d_in[3];
    const float* lnb  = (const float*)d_in[4];
    const float* w2   = (const float*)d_in[5];
    const float* b2   = (const float*)d_in[6];
    const float* ew1  = (const float*)d_in[7];
    const float* eb1  = (const float*)d_in[8];
    const float* ew2  = (const float*)d_in[9];
    const float* eb2  = (const float*)d_in[10];
    const float* gw1  = (const float*)d_in[11];
    const float* gb1  = (const float*)d_in[12];
    const float* gw2  = (const float*)d_in[13];
    const float* gb2  = (const float*)d_in[14];
    const float* sw   = (const float*)d_in[15];
    const float* sb   = (const float*)d_in[16];
    const float* hw1  = (const float*)d_in[17];
    const float* hb1  = (const float*)d_in[18];
    const float* hw2  = (const float*)d_in[19];
    const float* hb2  = (const float*)d_in[20];
    float* out = (float*)d_out;
    f16* ws = (f16*)d_ws;

    hipLaunchKernelGGL(prep_weights, dim3(64), dim3(256), 0, stream,
                       w1, w2, gw1, ew1, ew2, sw, hw1, ws);

    const int B = in_sizes[0] / 256;
    const int grid = B / 128;
    hipLaunchKernelGGL(fused_net_mfma, dim3(grid), dim3(256), 0, stream,
                       x, ws, b1, lng, lnb, b2, eb1, eb2, gb1, gw2, gb2,
                       sb, hb1, hw2, hb2, out);
}